// Round 16
// baseline (667.575 us; speedup 1.0000x reference)
//
#include <hip/hip_runtime.h>
#include <hip/hip_bf16.h>

// Problem constants (from reference)
#define BT 4096
#define HD 2048
#define VD 32000
#define IGNORE_IDX (-100)

// ---- 128x128 i8 GEMM geometry (fast path, 3 blocks/CU) ----
#define BM 128
#define BN 128
#define BK 64
#define NRB (BT / BM)  // 32
#define NCB (VD / BN)  // 250
#define NKT (HD / BK)  // 32

using short8 = __attribute__((ext_vector_type(8))) short;
using f32x4 = __attribute__((ext_vector_type(4))) float;
using i32x4 = __attribute__((ext_vector_type(4))) int;

__device__ __forceinline__ unsigned short f2bf(float f) {
  unsigned u = __float_as_uint(f);
  u = (u + 0x7fffu + ((u >> 16) & 1u)) >> 16;
  return (unsigned short)u;
}

// async global->LDS, 16B/lane; LDS dest = wave-uniform base + lane*16.
// offset param MUST stay 0 (R3/R4 NaN root cause) -- all offsets folded
// into the global pointer.
#define GL(SRC, DST)                                         \
  __builtin_amdgcn_global_load_lds(                          \
      (const __attribute__((address_space(1))) void*)(SRC),  \
      (__attribute__((address_space(3))) void*)(DST), 16, 0, 0)

// stage one full 128x64 i8 tile half per wave: wave w covers i-blocks
// {2w, 2w+1}; 2 issues per thread (j = row-block within wave region).
#define STG(GSRC, KOFF, DBASE, BUF)                          \
  GL((GSRC) + (KOFF), (DBASE) + (BUF)*8192);                 \
  GL((GSRC) + (KOFF) + 16 * HD, (DBASE) + (BUF)*8192 + 1024)

// ---------------------------------------------------------------------------
// Detect whether target buffer is int64 or int32 (reads 16KB, safe either way)
// ---------------------------------------------------------------------------
__global__ void detect_tgt_kernel(const long long* __restrict__ t64,
                                  int* __restrict__ badcnt) {
  int i = blockIdx.x * blockDim.x + threadIdx.x;  // 2048 threads
  long long v = t64[i];
  bool valid = (v == (long long)IGNORE_IDX) || (v >= 0 && v < (long long)VD);
  if (!valid) atomicAdd(badcnt, 1);
}

// ---------------------------------------------------------------------------
// Per-row symmetric int8 quantization: one block per row of [nrows][HD] fp32.
// ---------------------------------------------------------------------------
__global__ __launch_bounds__(256) void quant_rows_kernel(
    const float* __restrict__ in, signed char* __restrict__ outq,
    float* __restrict__ scale) {
  const int row = blockIdx.x;
  const int t = threadIdx.x;
  const float* src = in + (size_t)row * HD;
  float4 v0 = ((const float4*)src)[2 * t];
  float4 v1 = ((const float4*)src)[2 * t + 1];
  float vv[8] = {v0.x, v0.y, v0.z, v0.w, v1.x, v1.y, v1.z, v1.w};
  float amax = 0.f;
#pragma unroll
  for (int i = 0; i < 8; i++) amax = fmaxf(amax, fabsf(vv[i]));
#pragma unroll
  for (int m = 1; m < 64; m <<= 1) amax = fmaxf(amax, __shfl_xor(amax, m, 64));
  __shared__ float wm4[4];
  if ((t & 63) == 0) wm4[t >> 6] = amax;
  __syncthreads();
  float am = fmaxf(fmaxf(wm4[0], wm4[1]), fmaxf(wm4[2], wm4[3]));
  float inv = am > 0.f ? 127.f / am : 0.f;
  if (t == 0) scale[row] = am > 0.f ? am / 127.f : 0.f;
  int lo = 0, hi = 0;
#pragma unroll
  for (int i = 0; i < 4; i++) {
    float f = fminf(fmaxf(vv[i] * inv, -127.f), 127.f);
    lo |= (__float2int_rn(f) & 0xff) << (8 * i);
  }
#pragma unroll
  for (int i = 0; i < 4; i++) {
    float f = fminf(fmaxf(vv[4 + i] * inv, -127.f), 127.f);
    hi |= (__float2int_rn(f) & 0xff) << (8 * i);
  }
  int2 pk = make_int2(lo, hi);
  *(int2*)(outq + (size_t)row * HD + t * 8) = pk;
}

// ---------------------------------------------------------------------------
// FAST PATH: 128x128 int8 GEMM, BK=64, 32KB LDS double-buffer, 4 waves,
// 3 blocks/CU co-resident (the latency-hiding lever: barrier/vmcnt stalls of
// one block overlap other blocks' MFMA -- m97/m114 mechanism). Simple
// 2-barrier-per-tile loop, counted vmcnt(4). Fused scaled-exp epilogue.
//
// All R5-R15 proven elements kept:
//  - offset-0 global_load_lds, offsets folded into pointer
//  - FRAGMENT-ORDER LDS: tile (128 rows x 64 k i8) = 8 i-blocks x 1KB;
//    element (row=16i+fr, k=kq*16+j) at byte i*1024 + (kq*16+fr)*16 + j.
//    Staging LDS-linear (lane*16B), per-lane global source permuted
//    (srow=lane&15, scol=(lane>>4)*16B). ds_read lane-linear: 0 conflicts.
//  - within-tile register lifetimes only (no spill)
// Per tile per wave: 8 ds_read_b128 (4 A + 4 B), 16 mfma_i32_16x16x64_i8,
// 4 staging issues per thread-pair region.
// Sync per tile: RD; lgkm(0); BARRIER(all reads done -> WAR-safe);
// STG(kt+2 -> same buf); MFMA; vmcnt(4)(tile kt+1 landed); BARRIER.
// Ledger: enter tile kt with 4 outstanding {kt+1}; +4 stage -> 8;
// vmcnt(4) drains exactly tile kt+1's 4. Prologue stages tiles 0,1;
// vmcnt(4) drains tile 0. Tail: vmcnt(0) before tile NKT-1's reads.
// launch_bounds(256,3): 3 waves/EU floor -> VGPR cap ~170, no spill
// (acc 64 AGPR + ~70 arch), 3 blocks/CU by LDS (96KB) and VGPR.
// ---------------------------------------------------------------------------
__global__ __launch_bounds__(256, 3) void gemm_lse_i8_128_kernel(
    const signed char* __restrict__ xq, const signed char* __restrict__ wq,
    const float* __restrict__ sx, const float* __restrict__ sw,
    const void* __restrict__ tgt, const int* __restrict__ badcnt,
    float* __restrict__ partialS, float* __restrict__ picked) {
  __shared__ signed char smem[32768];  // 32 KB: A 16KB | B 16KB
  signed char* ldsA = smem;            // 2 bufs * 8192 B
  signed char* ldsB = smem + 16384;

  const int t = threadIdx.x;

  // zero-init LDS (defensive: residual bug -> finite-wrong, never NaN)
  {
    uint4 z = make_uint4(0u, 0u, 0u, 0u);
#pragma unroll
    for (int i = 0; i < 8; i++) ((uint4*)smem)[t + i * 256] = z;
  }
  __syncthreads();

  // T1: bijective XCD swizzle (8000 % 8 == 0), rowblock-fast
  const int bid = blockIdx.x;
  const int cpx = (NRB * NCB) >> 3;  // 1000
  const int swz = (bid & 7) * cpx + (bid >> 3);
  const int rb = swz % NRB;
  const int cb = swz / NRB;
  const int row0 = rb * BM;
  const int col0 = cb * BN;

  const int lane = t & 63;
  const int w = t >> 6;   // 0..3
  const int wm = w >> 1;  // 0..1 (A half: 64 rows)
  const int wn = w & 1;   // 0..1 (B half: 64 cols)

  const int fr = lane & 15;
  const int kq = lane >> 4;  // 0..3

  // read-side LDS bases (fragment-order): lane-linear, conflict-free
  const signed char* pA = ldsA + wm * 4096 + lane * 16;
  const signed char* pB = ldsB + wn * 4096 + lane * 16;

  // staging: wave w stages i-blocks {2w, 2w+1}; lane l = kq*16+fr sources
  // global (row = w*32 + j*16 + (l&15), kbyte = (l>>4)*16), lands at LDS
  // linear l*16B within the 1KB i-block region -> fragment-order layout.
  const int srow = lane & 15;
  const int scol = (lane >> 4) * 16;  // bytes
  const signed char* gA = xq + (size_t)(row0 + w * 32 + srow) * HD + scol;
  const signed char* gB = wq + (size_t)(col0 + w * 32 + srow) * HD + scol;

  signed char* dA = ldsA + w * 2048;  // wave's 2KB region within a buffer
  signed char* dB = ldsB + w * 2048;

  i32x4 acc[4][4];
#pragma unroll
  for (int i = 0; i < 4; i++)
#pragma unroll
    for (int n = 0; n < 4; n++)
#pragma unroll
      for (int q = 0; q < 4; q++) acc[i][n][q] = 0;

  i32x4 aF[4], bF[4];

#define RD(BUF)                                                      \
  _Pragma("unroll") for (int i = 0; i < 4; i++)                      \
      aF[i] = *(const i32x4*)(pA + (BUF)*8192 + i * 1024);           \
  _Pragma("unroll") for (int n = 0; n < 4; n++)                      \
      bF[n] = *(const i32x4*)(pB + (BUF)*8192 + n * 1024);

#define MM()                                                         \
  _Pragma("unroll") for (int i = 0; i < 4; i++)                      \
  _Pragma("unroll") for (int n = 0; n < 4; n++)                      \
      acc[i][n] = __builtin_amdgcn_mfma_i32_16x16x64_i8(             \
          aF[i], bF[n], acc[i][n], 0, 0, 0);

  // ---- prologue: stage tiles 0 (buf0) and 1 (buf1); drain tile0 ----
  STG(gA, 0, dA, 0);   // A(0)
  STG(gB, 0, dB, 0);   // B(0)
  STG(gA, 64, dA, 1);  // A(1)
  STG(gB, 64, dB, 1);  // B(1)
  asm volatile("s_waitcnt vmcnt(4)" ::: "memory");  // tile0 landed
  __builtin_amdgcn_s_barrier();

  // ---- main loop: 2 tiles/iter (buf0, buf1); stages tiles kt+2, kt+3 ----
  for (int kt = 0; kt + 3 < NKT; kt += 2) {
    // tile kt (buf0)
    RD(0);
    asm volatile("s_waitcnt lgkmcnt(0)" ::: "memory");  // my reads in regs
    __builtin_amdgcn_s_barrier();       // all waves' reads of buf0 done
    STG(gA, 128, dA, 0);                // A(kt+2) -> buf0
    STG(gB, 128, dB, 0);                // B(kt+2)
    __builtin_amdgcn_s_setprio(1);
    MM();
    __builtin_amdgcn_s_setprio(0);
    asm volatile("s_waitcnt vmcnt(4)" ::: "memory");  // tile kt+1 landed
    __builtin_amdgcn_s_barrier();
    // tile kt+1 (buf1)
    RD(1);
    asm volatile("s_waitcnt lgkmcnt(0)" ::: "memory");
    __builtin_amdgcn_s_barrier();       // all waves' reads of buf1 done
    STG(gA, 192, dA, 1);                // A(kt+3) -> buf1
    STG(gB, 192, dB, 1);                // B(kt+3)
    __builtin_amdgcn_s_setprio(1);
    MM();
    __builtin_amdgcn_s_setprio(0);
    asm volatile("s_waitcnt vmcnt(4)" ::: "memory");  // tile kt+2 landed
    __builtin_amdgcn_s_barrier();
    gA += 128;  // advance 2 K-tiles (128 bytes)
    gB += 128;
  }

  // ---- tail: tiles NKT-2 (buf0), NKT-1 (buf1); no more staging ----
  {
    RD(0);
    asm volatile("s_waitcnt lgkmcnt(0)" ::: "memory");
    __builtin_amdgcn_s_setprio(1);
    MM();
    __builtin_amdgcn_s_setprio(0);
    asm volatile("s_waitcnt vmcnt(0)" ::: "memory");  // tile NKT-1 landed
    __builtin_amdgcn_s_barrier();
    RD(1);
    asm volatile("s_waitcnt lgkmcnt(0)" ::: "memory");
    __builtin_amdgcn_s_setprio(1);
    MM();
    __builtin_amdgcn_s_setprio(0);
  }

  // ---- epilogue: logits = acc * sx[row] * sw[col]; per-row sum(exp) ----
  // C/D layout: col = col0 + wn*64 + n*16 + fr ;
  //             row = row0 + wm*64 + i*16 + kq*4 + q
  __syncthreads();
  float* sxl = (float*)smem;     // [128] row scales
  float* swl = sxl + 128;        // [128] col scales
  float* red = swl + 128;        // [128 rows][2 wn] floats
  if (t < 128) {
    sxl[t] = sx[row0 + t];
    swl[t] = sw[col0 + t];
  }
  __syncthreads();
#pragma unroll
  for (int i = 0; i < 4; i++) {
#pragma unroll
    for (int q = 0; q < 4; q++) {
      int lrow = wm * 64 + i * 16 + kq * 4 + q;
      float sxr = sxl[lrow];
      float s = 0.f;
#pragma unroll
      for (int n = 0; n < 4; n++) {
        int lcol = wn * 64 + n * 16 + fr;
        s += __expf((float)acc[i][n][q] * sxr * swl[lcol]);
      }
#pragma unroll
      for (int m = 1; m < 16; m <<= 1) s += __shfl_xor(s, m, 64);
      if (fr == 0) red[lrow * 2 + wn] = s;
    }
  }
  __syncthreads();
  if (t < 128) {
    float S = red[t * 2 + 0] + red[t * 2 + 1];
    partialS[(size_t)cb * BT + row0 + t] = S;
  }

  // ---- picked target logit (single writer per row across the grid) ----
  const bool is64 = (*badcnt == 0);
#pragma unroll
  for (int i = 0; i < 4; i++) {
#pragma unroll
    for (int q = 0; q < 4; q++) {
      int lrow = wm * 64 + i * 16 + kq * 4 + q;
      int grow = row0 + lrow;
      long long tv = is64 ? ((const long long*)tgt)[grow]
                          : (long long)((const int*)tgt)[grow];
#pragma unroll
      for (int n = 0; n < 4; n++) {
        int lcol = wn * 64 + n * 16 + fr;
        int gcol = col0 + lcol;
        if (tv == (long long)gcol)
          picked[grow] = (float)acc[i][n][q] * sxl[lrow] * swl[lcol];
      }
    }
  }
#undef RD
#undef MM
}

// ---------------------------------------------------------------------------
// FALLBACK PATH (ws too small): fp32 inputs with on-the-fly cvt (R1 kernel)
// ---------------------------------------------------------------------------
__global__ __launch_bounds__(256) void gemm_lse_kernel(
    const float* __restrict__ x, const float* __restrict__ w,
    const void* __restrict__ tgt, const int* __restrict__ badcnt,
    float* __restrict__ partialS, float* __restrict__ picked) {
  __shared__ unsigned short As[BM][32];
  __shared__ unsigned short Bs[BN][32];

  const int bid = blockIdx.x;
  const int rb = bid % NRB;
  const int cb = bid / NRB;
  const int row0 = rb * BM;
  const int col0 = cb * BN;
  const int t = threadIdx.x;
  const int lane = t & 63;
  const int wave = t >> 6;
  const int wr = wave >> 1;
  const int wc = wave & 1;

  const int srow = t >> 3;
  const int scol = (t & 7) * 4;

  const float* xA = x + (size_t)row0 * HD;
  const float* wB = w + (size_t)col0 * HD;

  f32x4 acc[4][4];
#pragma unroll
  for (int i = 0; i < 4; i++)
#pragma unroll
    for (int j = 0; j < 4; j++)
#pragma unroll
      for (int q = 0; q < 4; q++) acc[i][j][q] = 0.f;

  float4 ra[4], rbv[4];

#define STAGE_LOAD(k0)                                                        \
  {                                                                           \
    _Pragma("unroll") for (int j = 0; j < 4; j++) {                           \
      ra[j] = *(const float4*)(xA + (size_t)(srow + j * 32) * HD + (k0) + scol); \
      rbv[j] = *(const float4*)(wB + (size_t)(srow + j * 32) * HD + (k0) + scol); \
    }                                                                         \
  }
#define STAGE_WRITE()                                                         \
  {                                                                           \
    _Pragma("unroll") for (int j = 0; j < 4; j++) {                           \
      ushort4 pa = make_ushort4(f2bf(ra[j].x), f2bf(ra[j].y), f2bf(ra[j].z),  \
                                f2bf(ra[j].w));                               \
      ushort4 pb = make_ushort4(f2bf(rbv[j].x), f2bf(rbv[j].y),               \
                                f2bf(rbv[j].z), f2bf(rbv[j].w));              \
      *(ushort4*)&As[srow + j * 32][scol] = pa;                               \
      *(ushort4*)&Bs[srow + j * 32][scol] = pb;                               \
    }                                                                         \
  }

  const int ks = (lane >> 4) * 8;
  const int fr = lane & 15;

  STAGE_LOAD(0);
  STAGE_WRITE();
  __syncthreads();

  for (int k0 = 0; k0 < HD; k0 += 32) {
    const bool notlast = (k0 + 32 < HD);
    if (notlast) STAGE_LOAD(k0 + 32);

    short8 af[4], bfv[4];
#pragma unroll
    for (int i = 0; i < 4; i++) {
      af[i] = *(const short8*)&As[wr * 64 + i * 16 + fr][ks];
      bfv[i] = *(const short8*)&Bs[wc * 64 + i * 16 + fr][ks];
    }
#pragma unroll
    for (int i = 0; i < 4; i++)
#pragma unroll
      for (int j = 0; j < 4; j++)
        acc[i][j] = __builtin_amdgcn_mfma_f32_16x16x32_bf16(af[i], bfv[j],
                                                            acc[i][j], 0, 0, 0);

    __syncthreads();
    if (notlast) STAGE_WRITE();
    __syncthreads();
  }
#undef STAGE_LOAD
#undef STAGE_WRITE

  float rsum[16];
#pragma unroll
  for (int mi = 0; mi < 4; mi++) {
#pragma unroll
    for (int r = 0; r < 4; r++) {
      float s = 0.f;
#pragma unroll
      for (int nj = 0; nj < 4; nj++) s += __expf(acc[mi][nj][r]);
      rsum[mi * 4 + r] = s;
    }
  }
#pragma unroll
  for (int m = 1; m < 16; m <<= 1) {
#pragma unroll
    for (int q = 0; q < 16; q++) rsum[q] += __shfl_xor(rsum[q], m, 64);
  }

  __syncthreads();
  float* red = (float*)&As[0][0];
  if (fr == 0) {
#pragma unroll
    for (int mi = 0; mi < 4; mi++)
#pragma unroll
      for (int r = 0; r < 4; r++)
        red[wave * 64 + mi * 16 + (lane >> 4) * 4 + r] = rsum[mi * 4 + r];
  }
  __syncthreads();

  if (t < BM) {
    int rl = t;
    int wrow = rl >> 6;
    float S = red[(wrow * 2 + 0) * 64 + (rl & 63)] +
              red[(wrow * 2 + 1) * 64 + (rl & 63)];
    partialS[(size_t)cb * BT + row0 + rl] = S;
  }

  const bool is64 = (*badcnt == 0);
#pragma unroll
  for (int mi = 0; mi < 4; mi++) {
#pragma unroll
    for (int r = 0; r < 4; r++) {
      int grow = row0 + wr * 64 + mi * 16 + ((lane >> 4) << 2) + r;
      long long tv = is64 ? ((const long long*)tgt)[grow]
                          : (long long)((const int*)tgt)[grow];
#pragma unroll
      for (int nj = 0; nj < 4; nj++) {
        int gcol = col0 + wc * 64 + nj * 16 + fr;
        if (tv == (long long)gcol) picked[grow] = acc[mi][nj][r];
      }
    }
  }
}

// ---------------------------------------------------------------------------
// Per-row: S = sum of ncb partials; nll = log(S) - picked.
// ---------------------------------------------------------------------------
__global__ void reduce_rows_kernel(const float* __restrict__ partialS,
                                   const float* __restrict__ picked,
                                   float* __restrict__ nll, int ncb) {
  int r = blockIdx.x * blockDim.x + threadIdx.x;
  if (r >= BT) return;
  float S = 0.f;
  for (int cb = 0; cb < ncb; cb++) S += partialS[(size_t)cb * BT + r];
  nll[r] = logf(fmaxf(S, 1e-37f)) - picked[r];
}

// ---------------------------------------------------------------------------
// Final: loss = sum(nll) / n_non_ignore
// ---------------------------------------------------------------------------
__global__ void reduce_final_kernel(const float* __restrict__ nll,
                                    const void* __restrict__ tgt,
                                    const int* __restrict__ badcnt,
                                    float* __restrict__ out) {
  __shared__ float ssum[256];
  __shared__ int scnt[256];
  int t = threadIdx.x;
  const bool is64 = (*badcnt == 0);
  float s = 0.f;
  int c = 0;
  for (int r = t; r < BT; r += 256) {
    s += nll[r];
    long long tv =
        is64 ? ((const long long*)tgt)[r] : (long long)((const int*)tgt)[r];
    c += (tv != (long long)IGNORE_IDX) ? 1 : 0;
  }
  ssum[t] = s;
  scnt[t] = c;
  __syncthreads();
  for (int o = 128; o > 0; o >>= 1) {
    if (t < o) {
      ssum[t] += ssum[t + o];
      scnt[t] += scnt[t + o];
    }
    __syncthreads();
  }
  if (t == 0) out[0] = ssum[0] / (float)scnt[0];
}

// ---------------------------------------------------------------------------
extern "C" void kernel_launch(void* const* d_in, const int* in_sizes, int n_in,
                              void* d_out, int out_size, void* d_ws,
                              size_t ws_size, hipStream_t stream) {
  const float* x = (const float*)d_in[0];
  const float* w = (const float*)d_in[1];
  const void* tgt = d_in[2];
  float* out = (float*)d_out;

  char* ws = (char*)d_ws;
  // ws layout:
  //   [0, offA)              : partialS (NCB*BT*4 = 4,096,000 B)
  //   [offA, offA+16)        : badcnt flag (+pad)
  //   [offA+16, +BT*4)       : picked
  //   [.. +BT*4)             : nll
  //   [offX, +BT*HD)         : x as i8   (8 MB)
  //   [offW, +VD*HD)         : W as i8   (64 MB)
  //   [offSX, +BT*4)         : sx row scales
  //   [offSW, +VD*4)         : sw row scales
  const size_t offA = (size_t)NCB * BT * 4;
  float* partialS = (float*)ws;
  int* badcnt = (int*)(ws + offA);
  float* picked = (float*)(ws + offA + 16);
  float* nll = (float*)(ws + offA + 16 + (size_t)BT * 4);
  const size_t offX = offA + 16 + 2 * (size_t)BT * 4;
  const size_t offW = offX + (size_t)BT * HD;
  const size_t offSX = offW + (size_t)VD * HD;
  const size_t offSW = offSX + (size_t)BT * 4;
  const size_t need = offSW + (size_t)VD * 4;

  hipMemsetAsync(ws + offA, 0, 16 + (size_t)BT * 4, stream);

  detect_tgt_kernel<<<8, 256, 0, stream>>>((const long long*)tgt, badcnt);

  if (ws_size >= need) {
    signed char* xq = (signed char*)(ws + offX);
    signed char* wq = (signed char*)(ws + offW);
    float* sx = (float*)(ws + offSX);
    float* sw = (float*)(ws + offSW);
    quant_rows_kernel<<<BT, 256, 0, stream>>>(x, xq, sx);
    quant_rows_kernel<<<VD, 256, 0, stream>>>(w, wq, sw);
    gemm_lse_i8_128_kernel<<<NRB * NCB, 256, 0, stream>>>(
        xq, wq, sx, sw, tgt, badcnt, partialS, picked);
    reduce_rows_kernel<<<BT / 256, 256, 0, stream>>>(partialS, picked, nll,
                                                     NCB);
  } else {
    gemm_lse_kernel<<<NRB * NCB, 256, 0, stream>>>(x, w, tgt, badcnt, partialS,
                                                   picked);
    reduce_rows_kernel<<<BT / 256, 256, 0, stream>>>(partialS, picked, nll,
                                                     NCB);
  }

  reduce_final_kernel<<<1, 256, 0, stream>>>(nll, tgt, badcnt, out);
}